// Round 20
// baseline (325.880 us; speedup 1.0000x reference)
//
#include <hip/hip_runtime.h>

// BinaryTTN on MI355X — round 20.
// R19 clue: 2.1TB/s sustained at SAME dur -> not BW-bound; request-queue-bound.
// All MFMA-kernel global I/O was SCALAR dwords (64B/16-lane granule): 48 loads
// + 8 stores per pass (Common-mistake #2). R20: layout [site][n][16] (per-n
// contiguous) -> l = 4x dwordx4, r = 2x dwordx4, q = 2x dwordx4, store = 1x
// dwordx4 (1KB/wave fully covered). ~5x fewer requests. MFMA schedule, LDS
// staging, (256,5) bounds unchanged from R17.

#define NB 2048

typedef float f4 __attribute__((ext_vector_type(4)));
typedef float f32x4 __attribute__((ext_vector_type(4)));
typedef unsigned u32x4 __attribute__((ext_vector_type(4)));
typedef short bf16x8 __attribute__((ext_vector_type(8)));

#define MFMA(a, b, c) __builtin_amdgcn_mfma_f32_16x16x32_bf16(a, b, c, 0, 0, 0)

__device__ __forceinline__ unsigned pk2(float a, float b) {
  unsigned r;
  asm("v_cvt_pk_bf16_f32 %0, %1, %2" : "=v"(r) : "v"(a), "v"(b));
  return r;  // low16 = bf16(a), high16 = bf16(b)
}

// 3-way bf16 split of a pair (packed): x ~= h + m + l to ~2^-27 rel. (R8-exact)
__device__ __forceinline__ void split3(float a, float b,
                                       unsigned& h, unsigned& m, unsigned& l) {
  h = pk2(a, b);
  float ha = __uint_as_float(h << 16), hb = __uint_as_float(h & 0xffff0000u);
  float ra = a - ha, rb = b - hb;
  m = pk2(ra, rb);
  float ma = __uint_as_float(m << 16), mb = __uint_as_float(m & 0xffff0000u);
  l = pk2(ra - ma, rb - mb);
}

__device__ __forceinline__ bf16x8 asfrag(u32x4 x) {
  union { u32x4 u; bf16x8 f; } c; c.u = x; return c.f;
}

// FA[i] (stride 260 u32): [Wh j0-7 | Wh j8-15 | Wm j0-7 | Wm j8-15] per b.
// A3[i] (stride 132 u32): [Wl j0-7 | Wl j8-15]. Writes 2-way bank aliased (free).
__device__ __forceinline__ void stage_w(const float* __restrict__ wsite,
                                        unsigned* FA, unsigned* A3, int tid) {
  const int sb = tid >> 4, si = tid & 15;
  const float* wp = wsite + sb * 256 + si * 16;
  f4 v0 = *(const f4*)(wp + 0), v1 = *(const f4*)(wp + 4);
  f4 v2 = *(const f4*)(wp + 8), v3 = *(const f4*)(wp + 12);
  unsigned h[8], m[8], l[8];
  split3(v0.x, v0.y, h[0], m[0], l[0]); split3(v0.z, v0.w, h[1], m[1], l[1]);
  split3(v1.x, v1.y, h[2], m[2], l[2]); split3(v1.z, v1.w, h[3], m[3], l[3]);
  split3(v2.x, v2.y, h[4], m[4], l[4]); split3(v2.z, v2.w, h[5], m[5], l[5]);
  split3(v3.x, v3.y, h[6], m[6], l[6]); split3(v3.z, v3.w, h[7], m[7], l[7]);
  unsigned* fa = FA + si * 260 + sb * 4;
  *(u32x4*)(fa + 0)   = u32x4{h[0], h[1], h[2], h[3]};
  *(u32x4*)(fa + 64)  = u32x4{h[4], h[5], h[6], h[7]};
  *(u32x4*)(fa + 128) = u32x4{m[0], m[1], m[2], m[3]};
  *(u32x4*)(fa + 192) = u32x4{m[4], m[5], m[6], m[7]};
  unsigned* a3 = A3 + si * 132 + sb * 4;
  *(u32x4*)(a3 + 0)  = u32x4{l[0], l[1], l[2], l[3]};
  *(u32x4*)(a3 + 64) = u32x4{l[4], l[5], l[6], l[7]};
}

// Build the 3 B-operand variants from this lane's 8 r values (its jg half).
__device__ __forceinline__ void build_b(const float r[8], int lo,
                                        u32x4& b1, u32x4& b2, u32x4& b3) {
  unsigned bh[4], bm[4], bl[4];
  split3(r[0], r[1], bh[0], bm[0], bl[0]);
  split3(r[2], r[3], bh[1], bm[1], bl[1]);
  split3(r[4], r[5], bh[2], bm[2], bl[2]);
  split3(r[6], r[7], bh[3], bm[3], bl[3]);
  u32x4 vh{bh[0], bh[1], bh[2], bh[3]};
  u32x4 vm{bm[0], bm[1], bm[2], bm[3]};
  u32x4 vl{bl[0], bl[1], bl[2], bl[3]};
  b1 = lo ? vh : vm;
  b2 = lo ? vm : vh;
  b3 = lo ? vl : vh;
}

// ---- Transpose: x (n,c,64,64) -> xT[site1][n][8] (R5-proven, f4 both sides) ----
__global__ __launch_bounds__(256) void ttn_tx(
    const float* __restrict__ x, float* __restrict__ xT)
{
  const int x1 = blockIdx.x;            // 0..31
  const int y1 = threadIdx.x & 31;      // 0..31 (coalesced read dim)
  const int np = threadIdx.x >> 5;      // 0..7
  const int n  = blockIdx.y * 16 + np * 2;

  const float* xb = x + (long)n * 8192 + (2 * x1) * 64 + 2 * y1;
#pragma unroll
  for (int d = 0; d < 2; ++d) {
    const float* xd = xb + d * 8192;
    f4 q0 = {xd[0],    xd[1],    xd[64],   xd[65]};    // a00 a01 a10 a11
    f4 q1 = {xd[4096], xd[4097], xd[4160], xd[4161]};  // b00 b01 b10 b11
    float* op = xT + ((long)(x1 * 32 + y1) * NB + n + d) * 8;
    *reinterpret_cast<f4*>(op)     = q0;
    *reinterpret_cast<f4*>(op + 4) = q1;
  }
}

// ---- Fused L0+L1, MFMA (R17 schedule), vectorized I/O ----
__global__ __launch_bounds__(256, 5) void ttn_l0l1_mf(
    const float* __restrict__ xT, float* __restrict__ out,
    const float* __restrict__ w0, const float* __restrict__ w1)
{
  __shared__ unsigned FA[4160], A3[2112];
  const int s1 = blockIdx.x;
  const int x1 = s1 >> 5, y1 = s1 & 31;
  const int tid = threadIdx.x;
  stage_w(w1 + (long)s1 * 4096, FA, A3, tid);
  __syncthreads();

  const int lane = tid & 63;
  const int col = lane & 15, kg = lane >> 4, jg = kg & 1;
  const int lo = (kg < 2);
  const unsigned* fap = FA + (kg * 16 + col) * 4;
  const unsigned* fbp0 = lo ? fap : (A3 + ((kg - 2) * 16 + col) * 4);
  const int fbstr = lo ? 260 : 132;

  const float* w0s = w0 + (long)(x1 * 64 + 2 * y1) * 64;  // block-uniform base

  float wb[8][4];
#pragma unroll
  for (int jj = 0; jj < 8; ++jj) {
    f4 v = *(const f4*)(w0s + 64 + (jg * 8 + jj) * 4);
    wb[jj][0] = v.x; wb[jj][1] = v.y; wb[jj][2] = v.z; wb[jj][3] = v.w;
  }

  const float* xb8 = xT + (long)s1 * 8 * NB;
  float* outb = out + (long)s1 * 16 * NB;
  const long nb0 = (long)blockIdx.y * 512 + (tid >> 6) * 32 + col;

  for (int p = 0; p < 4; ++p) {
    const long nbase = nb0 + p * 128;
    u32x4 B1[2], B2[2], B3[2];
    float pa[2][4];
#pragma unroll
    for (int t = 0; t < 2; ++t) {
      const float* qp = xb8 + (nbase + t * 16) * 8;   // 32B contiguous per lane
      f4 va = *(const f4*)(qp);
      f4 vb = *(const f4*)(qp + 4);
      const float q0 = va.x, q1 = va.y, q2 = va.z, q3 = va.w;
      const float q4 = vb.x, q5 = vb.y, q6 = vb.z, q7 = vb.w;
      pa[t][0] = q0 * q2; pa[t][1] = q0 * q6; pa[t][2] = q4 * q2; pa[t][3] = q4 * q6;
      const float pb0 = q1 * q3, pb1 = q1 * q7, pb2 = q5 * q3, pb3 = q5 * q7;
      float r[8];
#pragma unroll
      for (int jj = 0; jj < 8; ++jj)
        r[jj] = wb[jj][0] * pb0 + wb[jj][1] * pb1 +
                wb[jj][2] * pb2 + wb[jj][3] * pb3;
      build_b(r, lo, B1[t], B2[t], B3[t]);
    }
    f32x4 acc0{0.f, 0.f, 0.f, 0.f}, acc1{0.f, 0.f, 0.f, 0.f};
    const unsigned* a1 = fap;
    const unsigned* a3v = fbp0;
#pragma unroll 2
    for (int i = 0; i < 16; ++i) {
      bf16x8 af1 = asfrag(*(const u32x4*)a1);  a1 += 260;
      bf16x8 af3 = asfrag(*(const u32x4*)a3v); a3v += fbstr;
      const float u0 = w0s[i * 4 + 0], u1 = w0s[i * 4 + 1];
      const float u2 = w0s[i * 4 + 2], u3 = w0s[i * 4 + 3];
      f32x4 z{0.f, 0.f, 0.f, 0.f};
      f32x4 c0 = MFMA(af1, asfrag(B1[0]), z);
      f32x4 c1 = MFMA(af1, asfrag(B1[1]), z);
      c0 = MFMA(af1, asfrag(B2[0]), c0);
      c1 = MFMA(af1, asfrag(B2[1]), c1);
      c0 = MFMA(af3, asfrag(B3[0]), c0);
      c1 = MFMA(af3, asfrag(B3[1]), c1);
      const float lv0 = u0 * pa[0][0] + u1 * pa[0][1] + u2 * pa[0][2] + u3 * pa[0][3];
      const float lv1 = u0 * pa[1][0] + u1 * pa[1][1] + u2 * pa[1][2] + u3 * pa[1][3];
      acc0 += c0 * lv0;
      acc1 += c1 * lv1;
    }
    // store: one dwordx4 per t; wave covers 1KB contiguous
    *(f4*)(outb + (nbase + 0)  * 16 + kg * 4) = acc0;
    *(f4*)(outb + (nbase + 16) * 16 + kg * 4) = acc1;
  }
}

// ---- Generic layer, MFMA, t=2 (R17 schedule), vectorized I/O ----
__global__ __launch_bounds__(256, 5) void ttn_mf(
    const float* __restrict__ in, float* __restrict__ out,
    const float* __restrict__ w, int outW, int prevW, int pairW, int np)
{
  __shared__ unsigned FA[4160], A3[2112];
  const int site = blockIdx.x;
  const int xs = site / outW, ys = site - xs * outW;
  int ls, rs;
  if (pairW) { ls = xs * prevW + 2 * ys; rs = ls + 1; }
  else       { ls = 2 * xs * prevW + ys; rs = ls + prevW; }

  const int tid = threadIdx.x;
  stage_w(w + (long)site * 4096, FA, A3, tid);
  __syncthreads();

  const int lane = tid & 63;
  const int col = lane & 15, kg = lane >> 4, jg = kg & 1;
  const int lo = (kg < 2);
  const unsigned* fap = FA + (kg * 16 + col) * 4;
  const unsigned* fbp0 = lo ? fap : (A3 + ((kg - 2) * 16 + col) * 4);
  const int fbstr = lo ? 260 : 132;

  const float* lb = in + (long)ls * 16 * NB;
  const float* rb = in + (long)rs * 16 * NB;
  float* outb = out + (long)site * 16 * NB;
  const long nb0 = (long)blockIdx.y * (128 * np) + (tid >> 6) * 32 + col;

  for (int p = 0; p < np; ++p) {
    const long nbase = nb0 + p * 128;
    u32x4 B1[2], B2[2], B3[2];
#pragma unroll
    for (int t = 0; t < 2; ++t) {
      const float* rp = rb + (nbase + t * 16) * 16 + jg * 8;  // 32B contiguous
      f4 ra = *(const f4*)(rp);
      f4 rc = *(const f4*)(rp + 4);
      float r[8] = {ra.x, ra.y, ra.z, ra.w, rc.x, rc.y, rc.z, rc.w};
      build_b(r, lo, B1[t], B2[t], B3[t]);
    }
    f32x4 acc0{0.f, 0.f, 0.f, 0.f}, acc1{0.f, 0.f, 0.f, 0.f};
    const unsigned* a1 = fap;
    const unsigned* a3v = fbp0;
    const float* lp0 = lb + (nbase + 0)  * 16;   // 64B contiguous per lane
    const float* lp1 = lb + (nbase + 16) * 16;
    for (int ic = 0; ic < 4; ++ic) {
      const f4 lv0 = *(const f4*)(lp0 + ic * 4);
      const f4 lv1 = *(const f4*)(lp1 + ic * 4);
#pragma unroll
      for (int ii = 0; ii < 4; ++ii) {
        bf16x8 af1 = asfrag(*(const u32x4*)a1);  a1 += 260;
        bf16x8 af3 = asfrag(*(const u32x4*)a3v); a3v += fbstr;
        f32x4 z{0.f, 0.f, 0.f, 0.f};
        f32x4 c0 = MFMA(af1, asfrag(B1[0]), z);
        f32x4 c1 = MFMA(af1, asfrag(B1[1]), z);
        c0 = MFMA(af1, asfrag(B2[0]), c0);
        c1 = MFMA(af1, asfrag(B2[1]), c1);
        c0 = MFMA(af3, asfrag(B3[0]), c0);
        c1 = MFMA(af3, asfrag(B3[1]), c1);
        acc0 += c0 * lv0[ii];
        acc1 += c1 * lv1[ii];
      }
    }
    *(f4*)(outb + (nbase + 0)  * 16 + kg * 4) = acc0;
    *(f4*)(outb + (nbase + 16) * 16 + kg * 4) = acc1;
  }
}

// ---- Layer 11: bond=1 -> d_out, [site][n][16] input, f4 loads ----
__global__ __launch_bounds__(256) void ttn_l11(
    const float* __restrict__ in, float* __restrict__ out,
    const float* __restrict__ w)
{
  __shared__ float Wl[256];
  const int tid = threadIdx.x;
  if (tid < 64)
    *(f4*)&Wl[tid * 4] = *(const f4*)(w + tid * 4);
  __syncthreads();

  const long n = (long)blockIdx.x * 256 + tid;
  const float* lp = in + n * 16;                  // site 0
  const float* rp = in + (long)16 * NB + n * 16;  // site 1
  float l[16], r[16];
#pragma unroll
  for (int c = 0; c < 4; ++c) {
    f4 lv = *(const f4*)(lp + 4 * c);
    f4 rv = *(const f4*)(rp + 4 * c);
    l[4 * c + 0] = lv.x; l[4 * c + 1] = lv.y; l[4 * c + 2] = lv.z; l[4 * c + 3] = lv.w;
    r[4 * c + 0] = rv.x; r[4 * c + 1] = rv.y; r[4 * c + 2] = rv.z; r[4 * c + 3] = rv.w;
  }
  float acc = 0.f;
#pragma unroll
  for (int i = 0; i < 16; ++i)
#pragma unroll
    for (int j = 0; j < 16; ++j) acc += Wl[i * 16 + j] * (l[i] * r[j]);
  out[n] = acc;
}

extern "C" void kernel_launch(void* const* d_in, const int* in_sizes, int n_in,
                              void* d_out, int out_size, void* d_ws, size_t ws_size,
                              hipStream_t stream) {
  const float* x = (const float*)d_in[0];
  const float* w[12];
  for (int k = 0; k < 12; ++k) w[k] = (const float*)d_in[1 + k];

  // R0: 16.78M floats (67.1 MB) — xT, then even-layer outputs
  // R1: 33.55M floats (134.2 MB) — odd-layer outputs. Total 201 MB (proven).
  float* R0 = (float*)d_ws;
  float* R1 = R0 + (size_t)1024 * 8 * NB;

  ttn_tx<<<dim3(32, NB / 16), 256, 0, stream>>>(x, R0);
  ttn_l0l1_mf<<<dim3(1024, 4), 256, 0, stream>>>(R0, R1, w[0], w[1]);

  ttn_mf<<<dim3(512, 4), 256, 0, stream>>>(R1, R0, w[2], 32, 32, 0, 4);   // L2
  ttn_mf<<<dim3(256, 4), 256, 0, stream>>>(R0, R1, w[3], 16, 32, 1, 4);   // L3
  ttn_mf<<<dim3(128, 4), 256, 0, stream>>>(R1, R0, w[4], 16, 16, 0, 4);   // L4
  ttn_mf<<<dim3(64, 4), 256, 0, stream>>>(R0, R1, w[5], 8, 16, 1, 4);     // L5
  ttn_mf<<<dim3(32, 16), 256, 0, stream>>>(R1, R0, w[6], 8, 8, 0, 1);     // L6
  ttn_mf<<<dim3(16, 16), 256, 0, stream>>>(R0, R1, w[7], 4, 8, 1, 1);     // L7
  ttn_mf<<<dim3(8, 16), 256, 0, stream>>>(R1, R0, w[8], 4, 4, 0, 1);      // L8
  ttn_mf<<<dim3(4, 16), 256, 0, stream>>>(R0, R1, w[9], 2, 4, 1, 1);      // L9
  ttn_mf<<<dim3(2, 16), 256, 0, stream>>>(R1, R0, w[10], 2, 2, 0, 1);     // L10
  ttn_l11<<<dim3(NB / 256), 256, 0, stream>>>(R0, (float*)d_out, w[11]);
}

// Round 21
// 259.121 us; speedup vs baseline: 1.2576x; 1.2576x over previous
//
#include <hip/hip_runtime.h>

// BinaryTTN on MI355X — round 21.
// R13-R20: eight structural fixes all leave l0l1 at 123-135us — the stall is
// invariant to LDS/VALU/occupancy/layout/vectorization. Last untouched knob:
// total MFMA work. R21 = R17 base with 2-split/4-product fp32 emulation
// (drop M3 = Wh*rl + Wl*rh, error ~2^-16/layer ~ 1e-4 final): MFMA/i 6->4,
// A3 LDS gone (25->16.6KB), build/stage splits -33% VALU. Single variable.

#define NB 2048

typedef float f4 __attribute__((ext_vector_type(4)));
typedef float f32x4 __attribute__((ext_vector_type(4)));
typedef unsigned u32x4 __attribute__((ext_vector_type(4)));
typedef short bf16x8 __attribute__((ext_vector_type(8)));

#define MFMA(a, b, c) __builtin_amdgcn_mfma_f32_16x16x32_bf16(a, b, c, 0, 0, 0)

__device__ __forceinline__ unsigned pk2(float a, float b) {
  unsigned r;
  asm("v_cvt_pk_bf16_f32 %0, %1, %2" : "=v"(r) : "v"(a), "v"(b));
  return r;  // low16 = bf16(a), high16 = bf16(b)
}

// 2-way bf16 split of a pair (packed): x ~= h + m to ~2^-16 rel.
__device__ __forceinline__ void split2(float a, float b,
                                       unsigned& h, unsigned& m) {
  h = pk2(a, b);
  float ha = __uint_as_float(h << 16), hb = __uint_as_float(h & 0xffff0000u);
  m = pk2(a - ha, b - hb);
}

__device__ __forceinline__ bf16x8 asfrag(u32x4 x) {
  union { u32x4 u; bf16x8 f; } c; c.u = x; return c.f;
}

// FA[i] (stride 260 u32): [Wh j0-7 | Wh j8-15 | Wm j0-7 | Wm j8-15] per b.
// Writes 2-way bank aliased (free); reads wave-contiguous 1KB.
__device__ __forceinline__ void stage_w(const float* __restrict__ wsite,
                                        unsigned* FA, int tid) {
  const int sb = tid >> 4, si = tid & 15;
  const float* wp = wsite + sb * 256 + si * 16;
  f4 v0 = *(const f4*)(wp + 0), v1 = *(const f4*)(wp + 4);
  f4 v2 = *(const f4*)(wp + 8), v3 = *(const f4*)(wp + 12);
  unsigned h[8], m[8];
  split2(v0.x, v0.y, h[0], m[0]); split2(v0.z, v0.w, h[1], m[1]);
  split2(v1.x, v1.y, h[2], m[2]); split2(v1.z, v1.w, h[3], m[3]);
  split2(v2.x, v2.y, h[4], m[4]); split2(v2.z, v2.w, h[5], m[5]);
  split2(v3.x, v3.y, h[6], m[6]); split2(v3.z, v3.w, h[7], m[7]);
  unsigned* fa = FA + si * 260 + sb * 4;
  *(u32x4*)(fa + 0)   = u32x4{h[0], h[1], h[2], h[3]};
  *(u32x4*)(fa + 64)  = u32x4{h[4], h[5], h[6], h[7]};
  *(u32x4*)(fa + 128) = u32x4{m[0], m[1], m[2], m[3]};
  *(u32x4*)(fa + 192) = u32x4{m[4], m[5], m[6], m[7]};
}

// Build the 2 B-operand variants from this lane's 8 r values (its jg half).
__device__ __forceinline__ void build_b(const float r[8], int lo,
                                        u32x4& b1, u32x4& b2) {
  unsigned bh[4], bm[4];
  split2(r[0], r[1], bh[0], bm[0]);
  split2(r[2], r[3], bh[1], bm[1]);
  split2(r[4], r[5], bh[2], bm[2]);
  split2(r[6], r[7], bh[3], bm[3]);
  u32x4 vh{bh[0], bh[1], bh[2], bh[3]};
  u32x4 vm{bm[0], bm[1], bm[2], bm[3]};
  b1 = lo ? vh : vm;
  b2 = lo ? vm : vh;
}

// ---------------- Transpose: x (n,c,64,64) -> xT[site1][q][n] (proven) ----
__global__ __launch_bounds__(256) void ttn_tx(
    const float* __restrict__ x, float* __restrict__ xT)
{
  __shared__ float S[4][32][65];
  const int x1 = blockIdx.x;
  const int n0 = blockIdx.y * 32;
  const int tid = threadIdx.x;
  const int lane = tid & 63;
  const int g = tid >> 6;
  const int c = g >> 1, rrow = g & 1;

  const float* xp = x + (long)n0 * 8192 + c * 4096 + (2 * x1 + rrow) * 64 + lane;
  for (int nn = 0; nn < 32; ++nn)
    S[g][nn][lane] = xp[(long)nn * 8192];
  __syncthreads();

  const int nl = tid & 31;
  const int yg = tid >> 5;
  for (int yy = 0; yy < 4; ++yy) {
    const int y1 = yg * 4 + yy;
    float* op = xT + (long)(x1 * 32 + y1) * 8 * NB + n0 + nl;
#pragma unroll
    for (int q = 0; q < 8; ++q) {
      const int cc = q >> 2, rr2 = (q >> 1) & 1, colq = q & 1;
      op[(long)q * NB] = S[cc * 2 + rr2][nl][2 * y1 + colq];
    }
  }
}

// ---------------- Fused L0+L1, MFMA, 2-term (R17 schedule) ----------------
__global__ __launch_bounds__(256, 5) void ttn_l0l1_mf(
    const float* __restrict__ xT, float* __restrict__ out,
    const float* __restrict__ w0, const float* __restrict__ w1)
{
  __shared__ unsigned FA[4160];
  const int s1 = blockIdx.x;
  const int x1 = s1 >> 5, y1 = s1 & 31;
  const int tid = threadIdx.x;
  stage_w(w1 + (long)s1 * 4096, FA, tid);
  __syncthreads();

  const int lane = tid & 63;
  const int col = lane & 15, kg = lane >> 4, jg = kg & 1;
  const int lo = (kg < 2);
  const unsigned* fap = FA + (kg * 16 + col) * 4;

  const float* w0s = w0 + (long)(x1 * 64 + 2 * y1) * 64;  // block-uniform base

  // per-lane W0 child-B rows (this lane's jg half) -> 32 VGPRs, once per block
  float wb[8][4];
#pragma unroll
  for (int jj = 0; jj < 8; ++jj) {
    f4 v = *(const f4*)(w0s + 64 + (jg * 8 + jj) * 4);
    wb[jj][0] = v.x; wb[jj][1] = v.y; wb[jj][2] = v.z; wb[jj][3] = v.w;
  }

  const float* xb = xT + (long)s1 * 8 * NB;
  const long nb0 = (long)blockIdx.y * 512 + (tid >> 6) * 32 + col;

  for (int p = 0; p < 4; ++p) {
    const long nbase = nb0 + p * 128;
    float qv[2][8];
#pragma unroll
    for (int t = 0; t < 2; ++t) {
      const float* qp = xb + nbase + t * 16;
#pragma unroll
      for (int d = 0; d < 8; ++d) qv[t][d] = qp[(long)d * NB];
    }
    u32x4 B1[2], B2[2];
    float pa[2][4];
#pragma unroll
    for (int t = 0; t < 2; ++t) {
      const float q0 = qv[t][0], q1 = qv[t][1], q2 = qv[t][2], q3 = qv[t][3];
      const float q4 = qv[t][4], q5 = qv[t][5], q6 = qv[t][6], q7 = qv[t][7];
      pa[t][0] = q0 * q2; pa[t][1] = q0 * q6; pa[t][2] = q4 * q2; pa[t][3] = q4 * q6;
      const float pb0 = q1 * q3, pb1 = q1 * q7, pb2 = q5 * q3, pb3 = q5 * q7;
      float r[8];
#pragma unroll
      for (int jj = 0; jj < 8; ++jj)
        r[jj] = wb[jj][0] * pb0 + wb[jj][1] * pb1 +
                wb[jj][2] * pb2 + wb[jj][3] * pb3;
      build_b(r, lo, B1[t], B2[t]);
    }
    f32x4 acc0{0.f, 0.f, 0.f, 0.f}, acc1{0.f, 0.f, 0.f, 0.f};
    const unsigned* a1 = fap;
#pragma unroll 2
    for (int i = 0; i < 16; ++i) {
      bf16x8 af1 = asfrag(*(const u32x4*)a1);  a1 += 260;
      // block-uniform -> s_load from scalar cache (no LDS, no VALU)
      const float u0 = w0s[i * 4 + 0], u1 = w0s[i * 4 + 1];
      const float u2 = w0s[i * 4 + 2], u3 = w0s[i * 4 + 3];
      f32x4 z{0.f, 0.f, 0.f, 0.f};
      f32x4 c0 = MFMA(af1, asfrag(B1[0]), z);
      f32x4 c1 = MFMA(af1, asfrag(B1[1]), z);
      c0 = MFMA(af1, asfrag(B2[0]), c0);
      c1 = MFMA(af1, asfrag(B2[1]), c1);
      const float lv0 = u0 * pa[0][0] + u1 * pa[0][1] + u2 * pa[0][2] + u3 * pa[0][3];
      const float lv1 = u0 * pa[1][0] + u1 * pa[1][1] + u2 * pa[1][2] + u3 * pa[1][3];
      acc0 += c0 * lv0;
      acc1 += c1 * lv1;
    }
    float* ob = out + ((long)s1 * 16 + kg * 4) * NB + nbase;
#pragma unroll
    for (int rg = 0; rg < 4; ++rg) {
      ob[(long)rg * NB] = acc0[rg];
      ob[(long)rg * NB + 16] = acc1[rg];
    }
  }
}

// ---------------- Generic layer, MFMA, t=2, 2-term (R17 schedule) ----------------
__global__ __launch_bounds__(256, 5) void ttn_mf(
    const float* __restrict__ in, float* __restrict__ out,
    const float* __restrict__ w, int outW, int prevW, int pairW, int np)
{
  __shared__ unsigned FA[4160];
  const int site = blockIdx.x;
  const int xs = site / outW, ys = site - xs * outW;
  int ls, rs;
  if (pairW) { ls = xs * prevW + 2 * ys; rs = ls + 1; }
  else       { ls = 2 * xs * prevW + ys; rs = ls + prevW; }

  const int tid = threadIdx.x;
  stage_w(w + (long)site * 4096, FA, tid);
  __syncthreads();

  const int lane = tid & 63;
  const int col = lane & 15, kg = lane >> 4, jg = kg & 1;
  const int lo = (kg < 2);
  const unsigned* fap = FA + (kg * 16 + col) * 4;

  const float* lb = in + (long)ls * 16 * NB;
  const float* rbj = in + (long)rs * 16 * NB + (long)jg * 8 * NB;

  for (int p = 0; p < np; ++p) {
    const long nbase = (long)blockIdx.y * (128 * np) + p * 128 + (tid >> 6) * 32 + col;
    u32x4 B1[2], B2[2];
#pragma unroll
    for (int t = 0; t < 2; ++t) {
      const float* rp = rbj + nbase + t * 16;
      float r[8];
#pragma unroll
      for (int jj = 0; jj < 8; ++jj) r[jj] = rp[(long)jj * NB];
      build_b(r, lo, B1[t], B2[t]);
    }
    f32x4 acc0{0.f, 0.f, 0.f, 0.f}, acc1{0.f, 0.f, 0.f, 0.f};
    const unsigned* a1 = fap;
    const float* lp = lb + nbase;
#pragma unroll 2
    for (int i = 0; i < 16; ++i) {
      bf16x8 af1 = asfrag(*(const u32x4*)a1);  a1 += 260;
      const float lv0 = lp[0], lv1 = lp[16];
      lp += NB;
      f32x4 z{0.f, 0.f, 0.f, 0.f};
      f32x4 c0 = MFMA(af1, asfrag(B1[0]), z);
      f32x4 c1 = MFMA(af1, asfrag(B1[1]), z);
      c0 = MFMA(af1, asfrag(B2[0]), c0);
      c1 = MFMA(af1, asfrag(B2[1]), c1);
      acc0 += c0 * lv0;
      acc1 += c1 * lv1;
    }
    float* ob = out + ((long)site * 16 + kg * 4) * NB + nbase;
#pragma unroll
    for (int rg = 0; rg < 4; ++rg) {
      ob[(long)rg * NB] = acc0[rg];
      ob[(long)rg * NB + 16] = acc1[rg];
    }
  }
}

// ---------------- Layer 11: bond=1 -> d_out (proven, exact fp32) ----------------
__global__ __launch_bounds__(256) void ttn_l11(
    const float* __restrict__ in, float* __restrict__ out,
    const float* __restrict__ w)
{
  __shared__ float Wl[256];
  const int tid = threadIdx.x;
  if (tid < 64)
    *(f4*)&Wl[tid * 4] = *(const f4*)(w + tid * 4);
  __syncthreads();

  const long n = (long)blockIdx.x * 256 + tid;
  float l[16], r[16];
#pragma unroll
  for (int i = 0; i < 16; ++i) l[i] = in[(long)i * NB + n];
#pragma unroll
  for (int j = 0; j < 16; ++j) r[j] = in[(long)(16 + j) * NB + n];
  float acc = 0.f;
#pragma unroll
  for (int i = 0; i < 16; ++i)
#pragma unroll
    for (int j = 0; j < 16; ++j) acc += Wl[i * 16 + j] * (l[i] * r[j]);
  out[n] = acc;
}

extern "C" void kernel_launch(void* const* d_in, const int* in_sizes, int n_in,
                              void* d_out, int out_size, void* d_ws, size_t ws_size,
                              hipStream_t stream) {
  const float* x = (const float*)d_in[0];
  const float* w[12];
  for (int k = 0; k < 12; ++k) w[k] = (const float*)d_in[1 + k];

  // R0: 16.78M floats (67.1 MB) — xT, then even-layer outputs
  // R1: 33.55M floats (134.2 MB) — odd-layer outputs. Total 201 MB (proven).
  float* R0 = (float*)d_ws;
  float* R1 = R0 + (size_t)1024 * 8 * NB;

  ttn_tx<<<dim3(32, NB / 32), 256, 0, stream>>>(x, R0);
  ttn_l0l1_mf<<<dim3(1024, 4), 256, 0, stream>>>(R0, R1, w[0], w[1]);

  ttn_mf<<<dim3(512, 4), 256, 0, stream>>>(R1, R0, w[2], 32, 32, 0, 4);   // L2
  ttn_mf<<<dim3(256, 4), 256, 0, stream>>>(R0, R1, w[3], 16, 32, 1, 4);   // L3
  ttn_mf<<<dim3(128, 4), 256, 0, stream>>>(R1, R0, w[4], 16, 16, 0, 4);   // L4
  ttn_mf<<<dim3(64, 4), 256, 0, stream>>>(R0, R1, w[5], 8, 16, 1, 4);     // L5
  ttn_mf<<<dim3(32, 16), 256, 0, stream>>>(R1, R0, w[6], 8, 8, 0, 1);     // L6
  ttn_mf<<<dim3(16, 16), 256, 0, stream>>>(R0, R1, w[7], 4, 8, 1, 1);     // L7
  ttn_mf<<<dim3(8, 16), 256, 0, stream>>>(R1, R0, w[8], 4, 4, 0, 1);      // L8
  ttn_mf<<<dim3(4, 16), 256, 0, stream>>>(R0, R1, w[9], 2, 4, 1, 1);      // L9
  ttn_mf<<<dim3(2, 16), 256, 0, stream>>>(R1, R0, w[10], 2, 2, 0, 1);     // L10
  ttn_l11<<<dim3(NB / 256), 256, 0, stream>>>(R0, (float*)d_out, w[11]);
}